// Round 4
// baseline (100.471 us; speedup 1.0000x reference)
//
#include <hip/hip_runtime.h>

// state[e, g, t, c] = sum_{s<=t} param_1 * disp[e, s]
// -> cumsum over t (T=128), broadcast over g (8) and c (6).
// Output [E, 8, 128, 6] fp32: write-bound (491.5 MB writes vs 10.2 MB reads).
// R3: nontemporal float4 stores (bypass L2 write-allocate): 102.3 -> 95.4 us.
// R4: 4 elements/block — all 4 waves scan in parallel (one per element),
//     then 24 store-iterations of contiguous NT stores. Amortizes the
//     prologue (load-latency + barrier) 4x over the store stream.

#define T_LEN 128
#define PER_ELEM (8 * T_LEN * 6)       // 6144 floats per element
#define EPB 4                          // elements per block (= waves per block)

typedef float f32x4 __attribute__((ext_vector_type(4)));

__global__ __launch_bounds__(256) void state_cumsum_bcast(
    const float* __restrict__ disp,    // [E, 128]
    const float* __restrict__ param1,  // [1]
    float* __restrict__ out,           // [E, 8, 128, 6]
    int n_elem) {
  __shared__ float cum[EPB][T_LEN];

  const int tid  = threadIdx.x;
  const int wv   = tid >> 6;           // wave id 0..3
  const int lane = tid & 63;
  const int e0   = blockIdx.x * EPB;

  // Each wave scans its own element: coalesced 256B loads, 64-lane shfl scan.
  const int es = e0 + wv;
  if (es < n_elem) {
    const float p = param1[0];
    float x0 = p * disp[(size_t)es * T_LEN + lane];
    float x1 = p * disp[(size_t)es * T_LEN + 64 + lane];
    #pragma unroll
    for (int d = 1; d < 64; d <<= 1) {
      float y0 = __shfl_up(x0, d, 64);
      float y1 = __shfl_up(x1, d, 64);
      if (lane >= d) { x0 += y0; x1 += y1; }
    }
    const float total0 = __shfl(x0, 63, 64);
    cum[wv][lane]      = x0;
    cum[wv][64 + lane] = x1 + total0;
  }
  __syncthreads();

  // Broadcast: 4 elements x 24 KB contiguous NT-store span each.
  // float index f in [0, 6144): t = (f/6) % 128, value = cum[el][t].
  #pragma unroll
  for (int el = 0; el < EPB; ++el) {
    const int e = e0 + el;
    if (e >= n_elem) break;
    f32x4* o4 = reinterpret_cast<f32x4*>(out + (size_t)e * PER_ELEM);
    #pragma unroll
    for (int i = 0; i < 6; ++i) {
      const int v = i * 256 + tid;
      const int f = v * 4;
      f32x4 w;
      w.x = cum[el][((f + 0) / 6) & (T_LEN - 1)];
      w.y = cum[el][((f + 1) / 6) & (T_LEN - 1)];
      w.z = cum[el][((f + 2) / 6) & (T_LEN - 1)];
      w.w = cum[el][((f + 3) / 6) & (T_LEN - 1)];
      __builtin_nontemporal_store(w, &o4[v]);
    }
  }
}

extern "C" void kernel_launch(void* const* d_in, const int* in_sizes, int n_in,
                              void* d_out, int out_size, void* d_ws, size_t ws_size,
                              hipStream_t stream) {
  const float* disp   = (const float*)d_in[0];  // [E, 128]
  const float* param1 = (const float*)d_in[1];  // [1]
  float* out = (float*)d_out;

  const int n_elem = in_sizes[0] / T_LEN;       // 20000
  const int n_blocks = (n_elem + EPB - 1) / EPB;

  state_cumsum_bcast<<<n_blocks, 256, 0, stream>>>(disp, param1, out, n_elem);
}